// Round 1
// baseline (290.468 us; speedup 1.0000x reference)
//
#include <hip/hip_runtime.h>

#define DD 32
#define DFF 256
#define BATCH_N 32768
#define ROWS 64
#define BD (BATCH_N * DD)

typedef __bf16 bf16x8 __attribute__((ext_vector_type(8)));
typedef unsigned short u16x8 __attribute__((ext_vector_type(8)));
typedef float f32x4 __attribute__((ext_vector_type(4)));

__device__ __forceinline__ unsigned short f2bf(float f) {
  unsigned int u = __builtin_bit_cast(unsigned int, f);
  u += 0x7FFFu + ((u >> 16) & 1u);            // round-to-nearest-even
  return (unsigned short)(u >> 16);
}
__device__ __forceinline__ float bf2f(unsigned short h) {
  unsigned int u = ((unsigned int)h) << 16;
  return __builtin_bit_cast(float, u);
}

// ---------------- weight repack: f32 row-major -> bf16 MFMA-fragment layout ----
// packed[((ks*NT + nt)*64 + lane)*8 + j] = W[ks*32 + (lane>>4)*8 + j][nt*16 + (lane&15)]
__global__ void repack_kernel(const float* __restrict__ src,
                              unsigned short* __restrict__ dst,
                              int K, int N, long sstride, long dstride) {
  long mat = blockIdx.y;
  int p = blockIdx.x * 256 + threadIdx.x;
  if (p >= K * N) return;
  int NT = N >> 4;
  int j = p & 7;
  int l = (p >> 3) & 63;
  int rest = p >> 9;
  int nt = rest % NT;
  int ks = rest / NT;
  int k = ks * 32 + ((l >> 4) << 3) + j;
  int n = nt * 16 + (l & 15);
  dst[mat * dstride + p] = f2bf(src[mat * sstride + (long)k * N + n]);
}

// ---------------- LDS addressing (XOR-swizzled to kill 512B-stride bank conflicts)
__device__ __forceinline__ int swzA(int row, int col) {   // [64][256] bf16
  return ((row * DFF + col) * 2) ^ ((row & 7) << 4);
}
__device__ __forceinline__ int swzY(int row, int k) {     // [64][32] bf16
  return ((row * DD + k) * 2) ^ ((row & 3) << 4);
}

__device__ __forceinline__ bf16x8 ldA(const unsigned short* buf, int row, int k0) {
  return __builtin_bit_cast(bf16x8, *(const uint4*)((const char*)buf + swzA(row, k0)));
}
__device__ __forceinline__ bf16x8 ldB(const unsigned short* wp, int ks, int NT, int nt, int lane) {
  return __builtin_bit_cast(bf16x8, *(const uint4*)(wp + ((((ks * NT + nt) << 6) + lane) << 3)));
}

#define MFMA16(a, b, c) __builtin_amdgcn_mfma_f32_16x16x32_bf16((a), (b), (c), 0, 0, 0)

__device__ __forceinline__ void zeroAcc(f32x4 acc[4][4]) {
  f32x4 z = {0.f, 0.f, 0.f, 0.f};
#pragma unroll
  for (int i = 0; i < 4; ++i)
#pragma unroll
    for (int j = 0; j < 4; ++j) acc[i][j] = z;
}

// 64xK @ KxN(=256) with K=256, A from swizzled LDS, B from packed global.
__device__ __forceinline__ void mm256(const unsigned short* A, const unsigned short* Bp,
                                      f32x4 acc[4][4], int lr, int lg, int wv) {
  const int lane = (lg << 4) | lr;
#pragma unroll
  for (int ks = 0; ks < 8; ++ks) {
    bf16x8 a[4];
#pragma unroll
    for (int rt = 0; rt < 4; ++rt) a[rt] = ldA(A, rt * 16 + lr, ks * 32 + lg * 8);
#pragma unroll
    for (int ct = 0; ct < 4; ++ct) {
      bf16x8 b = ldB(Bp, ks, 16, wv * 4 + ct, lane);
#pragma unroll
      for (int rt = 0; rt < 4; ++rt) acc[rt][ct] = MFMA16(a[rt], b, acc[rt][ct]);
    }
  }
}

// 64x32 @ 32x256 (one K-step), A from y-state LDS, causal mask k<=imask.
__device__ __forceinline__ void mm32(const unsigned short* Y, const unsigned short* Bp,
                                     f32x4 acc[4][4], int imask, int lr, int lg, int wv) {
  const int lane = (lg << 4) | lr;
  bf16x8 a[4];
#pragma unroll
  for (int rt = 0; rt < 4; ++rt) {
    int row = rt * 16 + lr;
    u16x8 s = __builtin_bit_cast(u16x8, *(const uint4*)((const char*)Y + swzY(row, lg * 8)));
#pragma unroll
    for (int j = 0; j < 8; ++j)
      if (lg * 8 + j > imask) s[j] = 0;
    a[rt] = __builtin_bit_cast(bf16x8, s);
  }
#pragma unroll
  for (int ct = 0; ct < 4; ++ct) {
    bf16x8 b = ldB(Bp, 0, 16, wv * 4 + ct, lane);
#pragma unroll
    for (int rt = 0; rt < 4; ++rt) acc[rt][ct] = MFMA16(a[rt], b, acc[rt][ct]);
  }
}

// epilogue: +bias, relu, bf16 -> swizzled LDS. C/D layout: col=lane&15, row=(lane>>4)*4+reg.
__device__ __forceinline__ void storeAct(unsigned short* dst, f32x4 acc[4][4],
                                         const float* __restrict__ bias,
                                         int lr, int lg, int wv) {
#pragma unroll
  for (int ct = 0; ct < 4; ++ct) {
    int col = wv * 64 + ct * 16 + lr;
    float bv = bias[col];
#pragma unroll
    for (int rt = 0; rt < 4; ++rt)
#pragma unroll
      for (int rr = 0; rr < 4; ++rr) {
        int row = rt * 16 + lg * 4 + rr;
        float v = fmaxf(acc[rt][ct][rr] + bv, 0.f);
        *(unsigned short*)((char*)dst + swzA(row, col)) = f2bf(v);
      }
  }
}

__global__ __launch_bounds__(256, 2)
void vae_kernel(const float* __restrict__ xin, const float* __restrict__ eps,
                const float* __restrict__ be1, const float* __restrict__ be2,
                const float* __restrict__ be3, const float* __restrict__ b1,
                const float* __restrict__ b2, const float* __restrict__ W3,
                const float* __restrict__ b3,
                const unsigned short* __restrict__ We1p,
                const unsigned short* __restrict__ We2p,
                const unsigned short* __restrict__ We3p,
                const unsigned short* __restrict__ W1p,
                const unsigned short* __restrict__ W2p,
                float* __restrict__ out) {
  __shared__ unsigned short bufA[ROWS * DFF];  // 32 KB: h1 / z(f32 overlay) / t1 / red overlay
  __shared__ unsigned short bufB[ROWS * DFF];  // 32 KB: h2 (encoder only)
  __shared__ unsigned short ybf[ROWS * DD];    // 4 KB: y state, bf16 (MFMA A operand)
  __shared__ float yf[ROWS * DD];              // 8 KB: y state, f32 (authoritative)

  const int tid = threadIdx.x;
  const int lane = tid & 63;
  const int wv = tid >> 6;
  const int lr = lane & 15;
  const int lg = lane >> 4;
  const long r0 = (long)blockIdx.x * ROWS;

  // ---- stage x rows into ybf (A operand for enc1, K = D = 32) ----
  for (int e = tid; e < ROWS * DD; e += 256) {
    int rr = e >> 5, d = e & 31;
    *(unsigned short*)((char*)ybf + swzY(rr, d)) = f2bf(xin[(r0 + rr) * DD + d]);
  }
  __syncthreads();

  f32x4 acc[4][4];

  // ---- enc1: h1 = relu(x @ We1 + be1) ----
  zeroAcc(acc);
  mm32(ybf, We1p, acc, 31, lr, lg, wv);   // imask=31: no masking
  storeAct(bufA, acc, be1, lr, lg, wv);
  __syncthreads();

  // ---- enc2: h2 = relu(h1 @ We2 + be2) ----
  zeroAcc(acc);
  mm256(bufA, We2p, acc, lr, lg, wv);
  storeAct(bufB, acc, be2, lr, lg, wv);
  __syncthreads();

  // ---- enc3: z = h2 @ We3 + be3  (N=64, wave owns 16 cols; f32 into bufA overlay) ----
  {
    f32x4 az[4];
    f32x4 z4 = {0.f, 0.f, 0.f, 0.f};
#pragma unroll
    for (int rt = 0; rt < 4; ++rt) az[rt] = z4;
#pragma unroll
    for (int ks = 0; ks < 8; ++ks) {
      bf16x8 b = ldB(We3p, ks, 4, wv, lane);
#pragma unroll
      for (int rt = 0; rt < 4; ++rt) {
        bf16x8 a = ldA(bufB, rt * 16 + lr, ks * 32 + lg * 8);
        az[rt] = MFMA16(a, b, az[rt]);
      }
    }
    float* zb = (float*)bufA;   // [64][66] f32 (16.9 KB < 32 KB)
    int col = wv * 16 + lr;
    float bz = be3[col];
#pragma unroll
    for (int rt = 0; rt < 4; ++rt)
#pragma unroll
      for (int rr = 0; rr < 4; ++rr) {
        int row = rt * 16 + lg * 4 + rr;
        zb[row * 66 + col] = az[rt][rr] + bz;
      }
  }
  __syncthreads();

  // ---- reparam: y0 = mu + exp(lv/2)*eps; emit mu, log_var ----
  {
    const float* zb = (const float*)bufA;
    for (int e = tid; e < ROWS * DD; e += 256) {
      int rr = e >> 5, d = e & 31;
      float mu = zb[rr * 66 + d];
      float lv = zb[rr * 66 + 32 + d];
      long gi = (r0 + rr) * DD + d;
      float y0 = mu + __expf(0.5f * lv) * eps[gi];
      yf[e] = y0;
      *(unsigned short*)((char*)ybf + swzY(rr, d)) = f2bf(y0);
      out[BD + gi] = mu;
      out[2L * BD + gi] = lv;
    }
  }
  __syncthreads();

  // ---- causal decoder: 32 sequential steps ----
  for (int i = 0; i < DD; ++i) {
    // t1 = relu((y * mask_i) @ W1[i] + b1[i])
    zeroAcc(acc);
    mm32(ybf, W1p + i * (DD * DFF), acc, i, lr, lg, wv);
    storeAct(bufA, acc, b1 + i * DFF, lr, lg, wv);
    __syncthreads();

    // t2 = relu(t1 @ W2[i] + b2[i]) — kept in registers (f32), fused with W3 dot
    zeroAcc(acc);
    mm256(bufA, W2p + i * (DFF * DFF), acc, lr, lg, wv);

    const float* w3r = W3 + i * DFF;
    const float* b2r = b2 + i * DFF;
    float part[4][4] = {};
#pragma unroll
    for (int ct = 0; ct < 4; ++ct) {
      int col = wv * 64 + ct * 16 + lr;
      float b2v = b2r[col];
      float w3v = w3r[col];
#pragma unroll
      for (int rt = 0; rt < 4; ++rt)
#pragma unroll
        for (int rr = 0; rr < 4; ++rr) {
          float t = fmaxf(acc[rt][ct][rr] + b2v, 0.f);
          part[rt][rr] = fmaf(t, w3v, part[rt][rr]);
        }
    }
    // reduce over the 16 lanes of each lg-group (cols within the wave's slice)
#pragma unroll
    for (int off = 1; off < 16; off <<= 1)
#pragma unroll
      for (int rt = 0; rt < 4; ++rt)
#pragma unroll
        for (int rr = 0; rr < 4; ++rr)
          part[rt][rr] += __shfl_xor(part[rt][rr], off, 64);

    __syncthreads();               // t1 (bufA) reads done -> reuse as reduction buffer
    float* red = (float*)bufA;     // [4 waves][64 rows]
    if (lr == 0) {
#pragma unroll
      for (int rt = 0; rt < 4; ++rt)
#pragma unroll
        for (int rr = 0; rr < 4; ++rr)
          red[wv * 64 + rt * 16 + lg * 4 + rr] = part[rt][rr];
    }
    __syncthreads();
    if (tid < ROWS) {
      float v = red[tid] + red[tid + 64] + red[tid + 128] + red[tid + 192] + b3[i];
      yf[tid * DD + i] = v;
      *(unsigned short*)((char*)ybf + swzY(tid, i)) = f2bf(v);
    }
    __syncthreads();
  }

  // ---- final y -> outputs 0 and 3 ----
  for (int e = tid; e < ROWS * DD; e += 256) {
    int rr = e >> 5, d = e & 31;
    long gi = (r0 + rr) * DD + d;
    float v = yf[e];
    out[gi] = v;
    out[3L * BD + gi] = v;
  }
}

extern "C" void kernel_launch(void* const* d_in, const int* in_sizes, int n_in,
                              void* d_out, int out_size, void* d_ws, size_t ws_size,
                              hipStream_t stream) {
  const float* xin = (const float*)d_in[0];
  // d_in[1] = m — unused by the reference
  const float* eps = (const float*)d_in[2];
  const float* We1 = (const float*)d_in[3];
  const float* be1 = (const float*)d_in[4];
  const float* We2 = (const float*)d_in[5];
  const float* be2 = (const float*)d_in[6];
  const float* We3 = (const float*)d_in[7];
  const float* be3 = (const float*)d_in[8];
  const float* W1  = (const float*)d_in[9];
  const float* b1  = (const float*)d_in[10];
  const float* W2  = (const float*)d_in[11];
  const float* b2  = (const float*)d_in[12];
  const float* W3  = (const float*)d_in[13];
  const float* b3  = (const float*)d_in[14];
  float* out = (float*)d_out;

  // packed bf16 weights in workspace (~4.9 MB)
  unsigned short* We1p = (unsigned short*)d_ws;
  unsigned short* We2p = We1p + 32 * 256;
  unsigned short* We3p = We2p + 256 * 256;
  unsigned short* W1p  = We3p + 256 * 64;
  unsigned short* W2p  = W1p + 32 * 32 * 256;

  repack_kernel<<<dim3(32, 1), 256, 0, stream>>>(We1, We1p, 32, 256, 0, 0);
  repack_kernel<<<dim3(256, 1), 256, 0, stream>>>(We2, We2p, 256, 256, 0, 0);
  repack_kernel<<<dim3(64, 1), 256, 0, stream>>>(We3, We3p, 256, 64, 0, 0);
  repack_kernel<<<dim3(32, 32), 256, 0, stream>>>(W1, W1p, 32, 256, 32 * 256, 32 * 256);
  repack_kernel<<<dim3(256, 32), 256, 0, stream>>>(W2, W2p, 256, 256, 256 * 256, 256 * 256);

  vae_kernel<<<dim3(BATCH_N / ROWS), 256, 0, stream>>>(
      xin, eps, be1, be2, be3, b1, b2, W3, b3, We1p, We2p, We3p, W1p, W2p, out);
}